// Round 1
// 269.922 us; speedup vs baseline: 1.0761x; 1.0761x over previous
//
#include <hip/hip_runtime.h>
#include <stdint.h>

#define T_TOK 8192
#define NEXP  8
#define DIMSZ 1024
#define HIDSZ 2048

typedef __attribute__((ext_vector_type(4))) float f32x4;
typedef __attribute__((ext_vector_type(8))) short s16x8;

// ---------- helpers ----------

__device__ __forceinline__ uint16_t f2bf(float f) {
  uint32_t u = __builtin_bit_cast(uint32_t, f);
  u += 0x7fffu + ((u >> 16) & 1u);   // RNE
  return (uint16_t)(u >> 16);
}

// async global->LDS, 16B per lane; LDS dst = wave-uniform base + lane*16.
__device__ __forceinline__ void gload_lds16(const uint16_t* g, const uint16_t* lds_base) {
  __builtin_amdgcn_global_load_lds(
      (const __attribute__((address_space(1))) uint32_t*)(uintptr_t)g,
      (__attribute__((address_space(3))) uint32_t*)(uint32_t)(uintptr_t)lds_base,
      16, 0, 0);
}

// ---------- fused convert (+ offsets in block 0) ----------
// 64B in / 32B out per thread per iteration: 4 independent dwordx4 loads
// in flight (double the MLP of the previous 32B version).

__global__ void cvt_all(const float* __restrict__ x, const float* __restrict__ w1,
                        const float* __restrict__ w2, uint16_t* __restrict__ xb,
                        uint16_t* __restrict__ w1b, uint16_t* __restrict__ w2b,
                        const int* __restrict__ counts, int* __restrict__ offs,
                        int* __restrict__ toffs) {
  if (blockIdx.x == 0 && threadIdx.x == 0) {
    int s = 0, ts = 0;
    for (int e = 0; e < NEXP; ++e) {
      offs[e] = s; toffs[e] = ts;
      s += counts[e]; ts += (counts[e] + 127) >> 7;
    }
    offs[NEXP] = s; toffs[NEXP] = ts;
  }
  const int NX = (T_TOK * DIMSZ) / 16;          // 64B units (16 floats each)
  const int NW = (NEXP * HIDSZ * DIMSZ) / 16;
  const int total = NX + 2 * NW;
  const int stride = gridDim.x * blockDim.x;
  for (int i = blockIdx.x * blockDim.x + threadIdx.x; i < total; i += stride) {
    const float* src; uint16_t* dst; int j;
    if (i < NX)           { src = x;  dst = xb;  j = i; }
    else if (i < NX + NW) { src = w1; dst = w1b; j = i - NX; }
    else                  { src = w2; dst = w2b; j = i - NX - NW; }
    const float4* p = (const float4*)src + 4 * (size_t)j;
    float4 a = p[0], b = p[1], c = p[2], d = p[3];
    uint4 o0, o1;
    o0.x = f2bf(a.x) | ((uint32_t)f2bf(a.y) << 16);
    o0.y = f2bf(a.z) | ((uint32_t)f2bf(a.w) << 16);
    o0.z = f2bf(b.x) | ((uint32_t)f2bf(b.y) << 16);
    o0.w = f2bf(b.z) | ((uint32_t)f2bf(b.w) << 16);
    o1.x = f2bf(c.x) | ((uint32_t)f2bf(c.y) << 16);
    o1.y = f2bf(c.z) | ((uint32_t)f2bf(c.w) << 16);
    o1.z = f2bf(d.x) | ((uint32_t)f2bf(d.y) << 16);
    o1.w = f2bf(d.z) | ((uint32_t)f2bf(d.w) << 16);
    uint4* q = (uint4*)dst + 2 * (size_t)j;
    q[0] = o0;
    q[1] = o1;
  }
}

// ---------- grouped NT GEMM ----------
// C[m,n] = sum_k A[m,k] * B_e[n,k].  Tile 128x128, BK=64 (m97 config), 4 waves.
// Compact 1-D grid: block b -> (mtile_global = b>>lognt, nt = b & (NT-1));
// expert found via device tile-offset table (<=71 m-tiles total).
// LDS rows are 64 bf16 = 8 x 16B chunks. Chunk-swizzle: global chunk Q of row
// R lives at chunk position Q ^ ((R>>1)&7)  => staging stays linear per wave
// call (global_load_lds requirement) and ds_read_b128 is <=2-way (free).
template <bool OUT_BF16>
__global__ __launch_bounds__(256, 3)
void gemm_grouped(const uint16_t* __restrict__ A, const uint16_t* __restrict__ B,
                  void* __restrict__ C, const int* __restrict__ offs,
                  const int* __restrict__ toffs, int N, int K, int lognt) {
  __shared__ __align__(16) uint16_t As[128 * 64];  // 16 KB
  __shared__ __align__(16) uint16_t Bs[128 * 64];  // 16 KB

  const int mtg = blockIdx.x >> lognt;
  const int nt  = blockIdx.x & ((1 << lognt) - 1);
  if (mtg >= toffs[NEXP]) return;
  int e = 0;
#pragma unroll
  for (int i = 1; i < NEXP; ++i) e += (toffs[i] <= mtg) ? 1 : 0;
  const int mt      = mtg - toffs[e];
  const int m_start = offs[e];
  const int m_count = offs[e + 1] - m_start;
  const int m0      = mt * 128;
  int valid_m = m_count - m0;
  if (valid_m > 128) valid_m = 128;
  const int n0 = nt * 128;

  const int tid  = threadIdx.x;
  const int w    = tid >> 6;
  const int lane = tid & 63;
  const int wm = w & 1, wn = w >> 1;

  const uint16_t* gA = A + (size_t)m_start * K;
  const uint16_t* gB = B + (size_t)e * N * K;

  // Staging: wave w owns rows [w*32, w*32+32). Call c covers rows w*32+c*8+[0,8).
  // Lane l lands at LDS byte (base + l*16) -> row +(l>>3), chunk pos l&7, which
  // must hold global chunk Q = (l&7) ^ ((row>>1)&7).
  const uint16_t* ap[4];
  const uint16_t* bp[4];
#pragma unroll
  for (int c = 0; c < 4; ++c) {
    const int r  = w * 32 + c * 8 + (lane >> 3);
    const int q8 = ((lane & 7) ^ ((r >> 1) & 7)) * 8;
    const int ra = (r < valid_m) ? r : (valid_m - 1);
    ap[c] = gA + (size_t)(m0 + ra) * K + q8;
    bp[c] = gB + (size_t)(n0 + r) * K + q8;
  }

  // Fragment read (swizzled): row = band + fr; k-half kk uses logical chunks
  // kk*4 + (lane>>4); swizzled element offset = f0 ^ (kk*32).
  const int fr = lane & 15;
  const int f0 = ((lane >> 4) ^ ((fr >> 1) & 7)) * 8;

  f32x4 acc[4][4];
#pragma unroll
  for (int mi = 0; mi < 4; ++mi)
#pragma unroll
    for (int ni = 0; ni < 4; ++ni) acc[mi][ni] = (f32x4){0.f, 0.f, 0.f, 0.f};

  for (int k0 = 0; k0 < K; k0 += 64) {
    __syncthreads();
#pragma unroll
    for (int c = 0; c < 4; ++c) {
      gload_lds16(ap[c], &As[(w * 32 + c * 8) * 64]);
      gload_lds16(bp[c], &Bs[(w * 32 + c * 8) * 64]);
    }
#pragma unroll
    for (int c = 0; c < 4; ++c) { ap[c] += 64; bp[c] += 64; }
    __syncthreads();

#pragma unroll
    for (int kk = 0; kk < 2; ++kk) {
      const int fk = f0 ^ (kk << 5);
      s16x8 af[4], bf[4];
#pragma unroll
      for (int mi = 0; mi < 4; ++mi)
        af[mi] = *(const s16x8*)&As[(wm * 64 + mi * 16 + fr) * 64 + fk];
#pragma unroll
      for (int ni = 0; ni < 4; ++ni)
        bf[ni] = *(const s16x8*)&Bs[(wn * 64 + ni * 16 + fr) * 64 + fk];
#pragma unroll
      for (int mi = 0; mi < 4; ++mi)
#pragma unroll
        for (int ni = 0; ni < 4; ++ni)
          acc[mi][ni] = __builtin_amdgcn_mfma_f32_16x16x32_bf16(af[mi], bf[ni], acc[mi][ni], 0, 0, 0);
    }
  }

  // Epilogue. C/D 16x16 layout: col = lane&15, row = (lane>>4)*4 + reg.
  const int cq = (lane >> 4) * 4;
  const int cc = lane & 15;
#pragma unroll
  for (int mi = 0; mi < 4; ++mi) {
#pragma unroll
    for (int r = 0; r < 4; ++r) {
      const int rt = wm * 64 + mi * 16 + cq + r;
      if (rt < valid_m) {
        const size_t rowoff = (size_t)(m_start + m0 + rt) * N;
#pragma unroll
        for (int ni = 0; ni < 4; ++ni) {
          const int col = n0 + wn * 64 + ni * 16 + cc;
          const float v = acc[mi][ni][r];
          if (OUT_BF16) {
            ((uint16_t*)C)[rowoff + col] = f2bf(v);
          } else {
            const uint32_t b = (uint32_t)f2bf(v) << 16;
            ((float*)C)[rowoff + col] = __builtin_bit_cast(float, b);
          }
        }
      }
    }
  }
}

// ---------- launch ----------

extern "C" void kernel_launch(void* const* d_in, const int* in_sizes, int n_in,
                              void* d_out, int out_size, void* d_ws, size_t ws_size,
                              hipStream_t stream) {
  const float* x  = (const float*)d_in[0];   // [T, DIM]
  const float* w1 = (const float*)d_in[1];   // [E, HID, DIM]
  const float* w2 = (const float*)d_in[2];   // [E, DIM, HID]
  const int* cnt  = (const int*)d_in[3];     // [E]
  float* out = (float*)d_out;                // [T, DIM] f32

  char* ws = (char*)d_ws;
  uint16_t* xb  = (uint16_t*)(ws);                      // 16 MB  [T, DIM] bf16
  uint16_t* w1b = (uint16_t*)(ws + 16777216);           // 32 MB  [E, HID, DIM] bf16
  uint16_t* w2b = (uint16_t*)(ws + 50331648);           // 32 MB  [E, DIM, HID] bf16
  uint16_t* h   = (uint16_t*)(ws + 83886080);           // 32 MB  [T, HID] bf16
  int* offs     = (int*)(ws + 117440512);               // 9 ints
  int* toffs    = offs + 9;                             // 9 ints

  cvt_all<<<2048, 256, 0, stream>>>(x, w1, w2, xb, w1b, w2b, cnt, offs, toffs);

  const int MAX_MT = T_TOK / 128 + NEXP - 1;            // 71: worst-case m-tiles

  // GEMM1: h = xb @ w1b^T  (N=HID=2048 -> 16 n-tiles, lognt=4, K=DIM)
  gemm_grouped<true><<<MAX_MT * 16, 256, 0, stream>>>(
      xb, w1b, (void*)h, offs, toffs, HIDSZ, DIMSZ, 4);

  // GEMM2: out = h @ w2b^T  (N=DIM=1024 -> 8 n-tiles, lognt=3, K=HID)
  gemm_grouped<false><<<MAX_MT * 8, 256, 0, stream>>>(
      h, w2b, (void*)out, offs, toffs, DIMSZ, HIDSZ, 3);
}